// Round 1
// baseline (266.076 us; speedup 1.0000x reference)
//
#include <hip/hip_runtime.h>
#include <math.h>

// YoloLayer decode: B=32, A=3, NC=80, H=W=76, stride=32.
// out layout: boxes [B, A, HW, 7] flat, then keep [B, A, HW] flat (0/1 floats).

namespace {
constexpr int kB   = 32;
constexpr int kA   = 3;
constexpr int kNC  = 80;
constexpr int kH   = 76;
constexpr int kW   = 76;
constexpr int kHW  = kH * kW;          // 5776
constexpr int kCPA = 5 + kNC;          // 85 channels per anchor
constexpr int kTot = kB * kA * kHW;    // 554496 threads, = 2166 * 256 exactly
}

__global__ __launch_bounds__(256)
void yolo_decode_kernel(const float* __restrict__ in,
                        const float* __restrict__ thrp,
                        float* __restrict__ out)
{
    const int t = blockIdx.x * 256 + threadIdx.x;
    if (t >= kTot) return;

    const float thresh = thrp[0];

    const int hw = t % kHW;
    const int ba = t / kHW;            // b*3 + a
    const int a  = ba % kA;

    // base pointer for this (b, anchor) at spatial position hw;
    // channel k lives at base + k*kHW (coalesced across lanes in hw).
    const float* __restrict__ base = in + (size_t)ba * kCPA * kHW + (size_t)hw;

    // head channels: x, y, w, h, obj
    const float x0 = base[0 * kHW];
    const float x1 = base[1 * kHW];
    const float x2 = base[2 * kHW];
    const float x3 = base[3 * kHW];
    const float x4 = base[4 * kHW];

    // ---- class logits into registers (static indexing, stays in VGPRs) ----
    float c[kNC];
    const float* __restrict__ cbase = base + 5 * kHW;
#pragma unroll
    for (int k = 0; k < kNC; ++k) c[k] = cbase[(size_t)k * kHW];

    // max logit (exact; fmax is order-insensitive for non-NaN)
    float m = c[0];
#pragma unroll
    for (int k = 1; k < kNC; ++k) m = fmaxf(m, c[k]);

    // softmax numerators; argmax over e with strict-> (first-index tie-break,
    // matching np.argmax over the softmax values)
    float s    = 0.0f;
    float emax = -1.0f;
    int   id   = 0;
#pragma unroll
    for (int k = 0; k < kNC; ++k) {
        const float e = expf(c[k] - m);
        s += e;
        if (e > emax) { emax = e; id = k; }
    }
    const float cls_conf = emax / s;

    // grid coords (row-major: ind = gy*W + gx)
    const int gx = hw % kW;
    const int gy = hw / kW;

    // anchors / stride, per-anchor (w,h)
    const float anchw[kA] = {116.0f / 32.0f, 156.0f / 32.0f, 373.0f / 32.0f};
    const float anchh[kA] = { 90.0f / 32.0f, 198.0f / 32.0f, 326.0f / 32.0f};

    constexpr float invW = 1.0f / (float)kW;
    constexpr float invH = 1.0f / (float)kH;

    const float sig0 = 1.0f / (1.0f + expf(-x0));
    const float sig1 = 1.0f / (1.0f + expf(-x1));
    const float det  = 1.0f / (1.0f + expf(-x4));

    const float xs = (sig0 + (float)gx) * invW;
    const float ys = (sig1 + (float)gy) * invH;
    const float ws = expf(x2) * anchw[a] * invW;
    const float hs = expf(x3) * anchh[a] * invH;

    // boxes: [B, A, HW, 7] row-major == t*7
    float* __restrict__ bp = out + (size_t)t * 7;
    bp[0] = xs;
    bp[1] = ys;
    bp[2] = ws;
    bp[3] = hs;
    bp[4] = det;
    bp[5] = cls_conf;
    bp[6] = (float)id;

    // keep: [B, A, HW] after the boxes block
    out[(size_t)kTot * 7 + t] = (det > thresh) ? 1.0f : 0.0f;
}

extern "C" void kernel_launch(void* const* d_in, const int* in_sizes, int n_in,
                              void* d_out, int out_size, void* d_ws, size_t ws_size,
                              hipStream_t stream) {
    (void)in_sizes; (void)n_in; (void)d_ws; (void)ws_size; (void)out_size;
    const float* in   = (const float*)d_in[0];
    const float* thrp = (const float*)d_in[1];
    float* out        = (float*)d_out;

    constexpr int kBlock = 256;
    constexpr int kGrid  = (kTot + kBlock - 1) / kBlock;   // 2166
    yolo_decode_kernel<<<kGrid, kBlock, 0, stream>>>(in, thrp, out);
}